// Round 8
// baseline (333.987 us; speedup 1.0000x reference)
//
#include <hip/hip_runtime.h>
#include <hip/hip_bf16.h>

#define D 64

typedef float vfloat4 __attribute__((ext_vector_type(4)));

__device__ __forceinline__ unsigned short f2bf(float f) {
    union { float f; unsigned u; } v; v.f = f;
    unsigned r = (v.u + 0x7FFF + ((v.u >> 16) & 1)) >> 16;   // RNE
    return (unsigned short)r;
}
__device__ __forceinline__ float bflo(unsigned u) {          // even col (bits 0-15)
    union { unsigned u; float f; } v; v.u = u << 16; return v.f;
}
__device__ __forceinline__ float bfhi(unsigned u) {          // odd col (bits 16-31)
    union { unsigned u; float f; } v; v.u = u & 0xFFFF0000u; return v.f;
}

// =============== K1: fused deg_count(+rank) and GEMM1 (hn = bf16(X @ W), unscaled) ===============
__global__ __launch_bounds__(256) void deg_and_gemm(
    const int* __restrict__ dst, int* __restrict__ deg, unsigned char* __restrict__ rank, int E, int nbD,
    const float* __restrict__ X, const float* __restrict__ W, unsigned short* __restrict__ hn, int N)
{
    __shared__ float sW[D * D];    // 16 KB
    __shared__ float sX[32 * D];   // 8 KB
    int tid = threadIdx.x;

    if ((int)blockIdx.x < nbD) {
        int stride = nbD * 256;
        for (int i = blockIdx.x * 256 + tid; i < E; i += stride) {
            int d = dst[i];
            rank[i] = (unsigned char)atomicAdd(&deg[d], 1);
        }
        return;
    }

    int rowBase = ((int)blockIdx.x - nbD) * 32;

    for (int i = tid; i < 1024; i += 256)
        ((vfloat4*)sW)[i] = ((const vfloat4*)W)[i];
    for (int i = tid; i < 512; i += 256) {
        int r = rowBase + (i >> 4);
        vfloat4 v = (vfloat4)0.0f;
        if (r < N) v = __builtin_nontemporal_load(((const vfloat4*)X) + rowBase * 16 + i);
        ((vfloat4*)sX)[i] = v;
    }
    __syncthreads();

    int wave = tid >> 6, lane = tid & 63;
    float accv[8];
#pragma unroll
    for (int r = 0; r < 8; ++r) accv[r] = 0.0f;

    int xoff = (wave * 8) * D;
#pragma unroll 8
    for (int k = 0; k < D; ++k) {
        float wv = sW[k * D + lane];
#pragma unroll
        for (int r = 0; r < 8; ++r)
            accv[r] += sX[xoff + r * D + k] * wv;
    }
#pragma unroll
    for (int r = 0; r < 8; ++r) {
        int row = rowBase + wave * 8 + r;
        if (row < N) hn[(size_t)row * D + lane] = f2bf(accv[r]);
    }
}

// =============== GEMM2: hn = bf16((h1 @ W) * dinv[row]) ===============
__global__ __launch_bounds__(256) void gemm2(
    const float* __restrict__ X, const float* __restrict__ W,
    const float* __restrict__ dinv, unsigned short* __restrict__ hn, int N)
{
    __shared__ float sW[D * D];
    __shared__ float sX[32 * D];
    int tid = threadIdx.x;
    int rowBase = blockIdx.x * 32;

    for (int i = tid; i < 1024; i += 256)
        ((vfloat4*)sW)[i] = ((const vfloat4*)W)[i];
    for (int i = tid; i < 512; i += 256) {
        int r = rowBase + (i >> 4);
        vfloat4 v = (vfloat4)0.0f;
        if (r < N) v = ((const vfloat4*)X)[rowBase * 16 + i];
        ((vfloat4*)sX)[i] = v;
    }
    __syncthreads();

    int wave = tid >> 6, lane = tid & 63;
    float accv[8];
#pragma unroll
    for (int r = 0; r < 8; ++r) accv[r] = 0.0f;

    int xoff = (wave * 8) * D;
#pragma unroll 8
    for (int k = 0; k < D; ++k) {
        float wv = sW[k * D + lane];
#pragma unroll
        for (int r = 0; r < 8; ++r)
            accv[r] += sX[xoff + r * D + k] * wv;
    }
#pragma unroll
    for (int r = 0; r < 8; ++r) {
        int row = rowBase + wave * 8 + r;
        if (row < N) hn[(size_t)row * D + lane] = f2bf(accv[r] * dinv[row]);
    }
}

// =============== K3: dinv + atomic block-scan for CSR range assignment ===============
__global__ __launch_bounds__(256) void dinv_scan(
    const int* __restrict__ deg, float* __restrict__ dinv,
    int* __restrict__ ofs, int* __restrict__ ctr, int N)
{
    __shared__ int lds[256];
    __shared__ int base;
    int tid = threadIdx.x, gid = blockIdx.x * 256 + tid;
    int v = (gid < N) ? deg[gid] : 0;
    if (gid < N) dinv[gid] = rsqrtf((float)(v + 1));   // +1 self loop
    lds[tid] = v;
    __syncthreads();
    for (int d2 = 1; d2 < 256; d2 <<= 1) {
        int t = (tid >= d2) ? lds[tid - d2] : 0;
        __syncthreads();
        lds[tid] += t;
        __syncthreads();
    }
    if (tid == 255) base = atomicAdd(ctr, lds[255]);
    __syncthreads();
    if (gid < N) ofs[gid] = base + lds[tid] - v;       // exclusive within range
}

// =============== K4: fused {atomic-free CSR fill} + {hn *= dinv[row]} ===============
__global__ __launch_bounds__(256) void fill_and_scale(
    const int* __restrict__ src, const int* __restrict__ dst,
    const unsigned char* __restrict__ rank, const int* __restrict__ ofs,
    int* __restrict__ csr, int E, int nbF,
    unsigned short* __restrict__ hn, const float* __restrict__ dinv, int N)
{
    int tid = threadIdx.x;
    if ((int)blockIdx.x < nbF) {
        int i = blockIdx.x * 256 + tid;
        if (i < E) {
            int d = dst[i];
            csr[ofs[d] + (int)rank[i]] = src[i];
        }
        return;
    }
    int cid = ((int)blockIdx.x - nbF) * 256 + tid;     // int4 chunk id
    if (cid >= N * 8) return;
    float f = dinv[cid >> 3];
    int4 h = ((int4*)hn)[cid];
    unsigned r0 = (unsigned)f2bf(bflo(h.x) * f) | ((unsigned)f2bf(bfhi(h.x) * f) << 16);
    unsigned r1 = (unsigned)f2bf(bflo(h.y) * f) | ((unsigned)f2bf(bfhi(h.y) * f) << 16);
    unsigned r2 = (unsigned)f2bf(bflo(h.z) * f) | ((unsigned)f2bf(bfhi(h.z) * f) << 16);
    unsigned r3 = (unsigned)f2bf(bflo(h.w) * f) | ((unsigned)f2bf(bfhi(h.w) * f) << 16);
    ((int4*)hn)[cid] = make_int4((int)r0, (int)r1, (int)r2, (int)r3);
}

// =============== K5: pull aggregation (bf16 int4 gather) + epilogue ===============
// one wave per node; 8 groups x 8 lanes; lane sub owns cols sub*8..sub*8+7 (one int4);
// group g handles neighbor positions j*8+g. hn is pre-scaled by dinv[src].
// NOTE: shfl must run with ALL lanes active (uniform trip count) — ds_bpermute
// does not publish data from exec-masked-off lanes.
__global__ __launch_bounds__(256) void aggregate_relu(
    const int* __restrict__ ofs, const int* __restrict__ deg,
    const int* __restrict__ csr, const unsigned short* __restrict__ hn,
    const float* __restrict__ dinv, const float* __restrict__ bias,
    float* __restrict__ out, int N)
{
    int wid  = (int)((blockIdx.x * 256 + threadIdx.x) >> 6);
    int lane = threadIdx.x & 63;
    if (wid >= N) return;
    int grp = lane >> 3, sub = lane & 7;

    const int4* hrow = (const int4*)hn;        // 8 int4 per row
    float a0 = 0.f, a1 = 0.f, a2 = 0.f, a3 = 0.f,
          a4 = 0.f, a5 = 0.f, a6 = 0.f, a7 = 0.f;

    if (grp == 0) {                            // self loop (pre-scaled)
        int4 h = hrow[(size_t)wid * 8 + sub];
        a0 += bflo(h.x); a1 += bfhi(h.x); a2 += bflo(h.y); a3 += bfhi(h.y);
        a4 += bflo(h.z); a5 += bfhi(h.z); a6 += bflo(h.w); a7 += bfhi(h.w);
    }

    int s0 = ofs[wid];
    int cnt = deg[wid];

    for (int t0 = 0; t0 < cnt; t0 += 64) {
        int p = t0 + lane;
        int idx = (p < cnt) ? csr[s0 + p] : 0;
        int m = cnt - t0; if (m > 64) m = 64;
        int jmax = (m + 7) >> 3;               // wave-uniform trip count
        for (int j = 0; j < jmax; ++j) {
            int pos = j * 8 + grp;             // < 64 always
            int sn = __shfl(idx, pos, 64);     // all 64 lanes active here
            if (pos < m) {
                int4 h = hrow[(size_t)sn * 8 + sub];
                a0 += bflo(h.x); a1 += bfhi(h.x); a2 += bflo(h.y); a3 += bfhi(h.y);
                a4 += bflo(h.z); a5 += bfhi(h.z); a6 += bflo(h.w); a7 += bfhi(h.w);
            }
        }
    }

    // reduce across the 8 groups (lanes with equal sub) — uniform code, all active
#pragma unroll
    for (int d2 = 8; d2 < 64; d2 <<= 1) {
        a0 += __shfl_xor(a0, d2, 64); a1 += __shfl_xor(a1, d2, 64);
        a2 += __shfl_xor(a2, d2, 64); a3 += __shfl_xor(a3, d2, 64);
        a4 += __shfl_xor(a4, d2, 64); a5 += __shfl_xor(a5, d2, 64);
        a6 += __shfl_xor(a6, d2, 64); a7 += __shfl_xor(a7, d2, 64);
    }

    if (grp == 0) {
        float dw = dinv[wid];
        float4 b0 = ((const float4*)bias)[sub * 2];
        float4 b1 = ((const float4*)bias)[sub * 2 + 1];
        float4 o0, o1;
        o0.x = fmaxf(a0 * dw + b0.x, 0.f);
        o0.y = fmaxf(a1 * dw + b0.y, 0.f);
        o0.z = fmaxf(a2 * dw + b0.z, 0.f);
        o0.w = fmaxf(a3 * dw + b0.w, 0.f);
        o1.x = fmaxf(a4 * dw + b1.x, 0.f);
        o1.y = fmaxf(a5 * dw + b1.y, 0.f);
        o1.z = fmaxf(a6 * dw + b1.z, 0.f);
        o1.w = fmaxf(a7 * dw + b1.w, 0.f);
        ((float4*)out)[(size_t)wid * 16 + sub * 2]     = o0;
        ((float4*)out)[(size_t)wid * 16 + sub * 2 + 1] = o1;
    }
}

// =============== launcher ===============

extern "C" void kernel_launch(void* const* d_in, const int* in_sizes, int n_in,
                              void* d_out, int out_size, void* d_ws, size_t ws_size,
                              hipStream_t stream) {
    const float* x   = (const float*)d_in[0];
    const int*   ei  = (const int*)d_in[1];   // [2, E] int32
    const float* W1  = (const float*)d_in[2];
    const float* b1  = (const float*)d_in[3];
    const float* W2  = (const float*)d_in[4];
    const float* b2  = (const float*)d_in[5];

    int N = in_sizes[0] / D;
    int E = in_sizes[1] / 2;
    const int* src = ei;
    const int* dst = ei + E;

    // workspace layout (bytes, ~24 MB total)
    char* ws = (char*)d_ws;
    int*            deg  = (int*)  (ws + 0x00000000);   // N ints
    int*            ctr  = (int*)  (ws + 0x00080000);   // 1 int
    float*          dinv = (float*)(ws + 0x00100000);   // N floats
    int*            ofs  = (int*)  (ws + 0x00180000);   // N ints
    unsigned char*  rank = (unsigned char*)(ws + 0x00200000);  // E bytes
    int*            csr  = (int*)  (ws + 0x003A0000);   // E ints (6.4 MB)
    unsigned short* hn   = (unsigned short*)(ws + 0x00A80000); // N*D bf16 (12.8 MB)
    float*          outF = (float*)d_out;

    int nb_N = (N + 255) / 256;
    int nb_E = (E + 255) / 256;
    int nb_G = (N + 31) / 32;
    int nb_A = (N + 3) / 4;
    int nb_S = (N * 8 + 255) / 256;          // scale blocks (int4 chunks)
    int nbD  = 1024;

    (void)hipMemsetAsync(deg, 0, (size_t)0x00080000 + 4, stream);  // deg + ctr

    // K1: deg/rank histogram overlapped with layer-1 GEMM (bf16 hn, unscaled)
    deg_and_gemm<<<nbD + nb_G, 256, 0, stream>>>(dst, deg, rank, E, nbD, x, W1, hn, N);
    // K3: dinv + CSR range assignment
    dinv_scan<<<nb_N, 256, 0, stream>>>(deg, dinv, ofs, ctr, N);
    // K4: CSR fill overlapped with hn *= dinv
    fill_and_scale<<<nb_E + nb_S, 256, 0, stream>>>(src, dst, rank, ofs, csr, E, nb_E, hn, dinv, N);

    // layer 1 aggregate -> h1 (fp32, in d_out)
    aggregate_relu<<<nb_A, 256, 0, stream>>>(ofs, deg, csr, hn, dinv, b1, outF, N);
    // layer 2 GEMM: hn = bf16((h1 @ W2) * dinv)
    gemm2<<<nb_G, 256, 0, stream>>>(outF, W2, dinv, hn, N);
    // layer 2 aggregate -> final out (in place over h1)
    aggregate_relu<<<nb_A, 256, 0, stream>>>(ofs, deg, csr, hn, dinv, b2, outF, N);
}

// Round 9
// 274.886 us; speedup vs baseline: 1.2150x; 1.2150x over previous
//
#include <hip/hip_runtime.h>
#include <hip/hip_bf16.h>

#define D 64
#define NB_HIST 256          // partition blocks (fixed ranges, pass A == pass B)
#define MAXBK 512            // supports N <= 131072 (buckets of 256 nodes)

typedef float vfloat4 __attribute__((ext_vector_type(4)));

__device__ __forceinline__ unsigned short f2bf(float f) {
    union { float f; unsigned u; } v; v.f = f;
    unsigned r = (v.u + 0x7FFF + ((v.u >> 16) & 1)) >> 16;   // RNE
    return (unsigned short)r;
}
__device__ __forceinline__ float bflo(unsigned u) {
    union { unsigned u; float f; } v; v.u = u << 16; return v.f;
}
__device__ __forceinline__ float bfhi(unsigned u) {
    union { unsigned u; float f; } v; v.u = u & 0xFFFF0000u; return v.f;
}

// =============== pass A: fused {per-block LDS bucket histogram} + GEMM1 ===============
// blocks [0, NB_HIST): LDS histogram of dst>>8 over fixed edge range -> blockCounts[b][bucket]
// blocks [NB_HIST, ...): hn = bf16(X @ W1) (unscaled)
__global__ __launch_bounds__(256) void passA_gemm(
    const int* __restrict__ dst, int* __restrict__ blockCounts, int E, int NBK,
    const float* __restrict__ X, const float* __restrict__ W,
    unsigned short* __restrict__ hn, int N)
{
    int tid = threadIdx.x;

    if ((int)blockIdx.x < NB_HIST) {
        __shared__ int hist[MAXBK];
        for (int i = tid; i < NBK; i += 256) hist[i] = 0;
        __syncthreads();
        int per = (E + NB_HIST - 1) / NB_HIST;
        int lo = blockIdx.x * per, hi = min(E, lo + per);
        for (int i = lo + tid; i < hi; i += 256)
            atomicAdd(&hist[dst[i] >> 8], 1);
        __syncthreads();
        for (int i = tid; i < NBK; i += 256)
            blockCounts[(size_t)blockIdx.x * NBK + i] = hist[i];
        return;
    }

    __shared__ float sW[D * D];
    __shared__ float sX[32 * D];
    int rowBase = ((int)blockIdx.x - NB_HIST) * 32;

    for (int i = tid; i < 1024; i += 256)
        ((vfloat4*)sW)[i] = ((const vfloat4*)W)[i];
    for (int i = tid; i < 512; i += 256) {
        int r = rowBase + (i >> 4);
        vfloat4 v = (vfloat4)0.0f;
        if (r < N) v = __builtin_nontemporal_load(((const vfloat4*)X) + rowBase * 16 + i);
        ((vfloat4*)sX)[i] = v;
    }
    __syncthreads();

    int wave = tid >> 6, lane = tid & 63;
    float accv[8];
#pragma unroll
    for (int r = 0; r < 8; ++r) accv[r] = 0.0f;
    int xoff = (wave * 8) * D;
#pragma unroll 8
    for (int k = 0; k < D; ++k) {
        float wv = sW[k * D + lane];
#pragma unroll
        for (int r = 0; r < 8; ++r)
            accv[r] += sX[xoff + r * D + k] * wv;
    }
#pragma unroll
    for (int r = 0; r < 8; ++r) {
        int row = rowBase + wave * 8 + r;
        if (row < N) hn[(size_t)row * D + lane] = f2bf(accv[r]);
    }
}

// =============== C1: per-bucket exclusive scan over the 256 blocks ===============
// one wave per bucket; partial[bucket][b] = sum_{b'<b} blockCounts[b'][bucket]; totals[bucket]
__global__ __launch_bounds__(256) void scan_cols(
    const int* __restrict__ blockCounts, int* __restrict__ partial,
    int* __restrict__ totals, int NBK)
{
    int wave = threadIdx.x >> 6, lane = threadIdx.x & 63;
    int k = blockIdx.x * 4 + wave;
    if (k >= NBK) return;
    int carry = 0;
    for (int base = 0; base < NB_HIST; base += 64) {
        int b = base + lane;
        int v = blockCounts[(size_t)b * NBK + k];
        int inc = v;
        for (int d = 1; d < 64; d <<= 1) {
            int t = __shfl_up(inc, d, 64);
            if (lane >= d) inc += t;
        }
        partial[(size_t)k * NB_HIST + b] = inc - v + carry;
        carry += __shfl(inc, 63, 64);
    }
    if (lane == 0) totals[k] = carry;
}

// =============== C2: exclusive scan of bucket totals (single wave) ===============
__global__ void scan_buckets(const int* __restrict__ totals, int* __restrict__ bofs, int NBK) {
    int lane = threadIdx.x;
    int carry = 0;
    for (int base = 0; base < NBK; base += 64) {
        int i = base + lane;
        int v = (i < NBK) ? totals[i] : 0;
        int inc = v;
        for (int d = 1; d < 64; d <<= 1) {
            int t = __shfl_up(inc, d, 64);
            if (lane >= d) inc += t;
        }
        if (i < NBK) bofs[i] = inc - v + carry;
        carry += __shfl(inc, 63, 64);
    }
}

// =============== pass B: scatter edges into bucket-grouped order (LDS cursors) ===============
// bucketed[pos] = (src << 8) | (dst & 255)   [src < 2^24 fits]
__global__ __launch_bounds__(256) void passB(
    const int* __restrict__ src, const int* __restrict__ dst,
    const int* __restrict__ bofs, const int* __restrict__ partial,
    int* __restrict__ bucketed, int E, int NBK)
{
    __shared__ int cur[MAXBK];
    int tid = threadIdx.x, b = blockIdx.x;
    for (int i = tid; i < NBK; i += 256)
        cur[i] = bofs[i] + partial[(size_t)i * NB_HIST + b];
    __syncthreads();
    int per = (E + NB_HIST - 1) / NB_HIST;
    int lo = b * per, hi = min(E, lo + per);
    for (int i = lo + tid; i < hi; i += 256) {
        int d = dst[i], s = src[i];
        int pos = atomicAdd(&cur[d >> 8], 1);
        bucketed[pos] = (s << 8) | (d & 255);
    }
}

// =============== level 2: per-bucket CSR build + deg/dinv/ofs + hn scale ===============
// one block per bucket (256 nodes); csr stores land in the bucket's ~16KB window (L2-merged)
__global__ __launch_bounds__(256) void build_csr_scale(
    const int* __restrict__ bucketed, const int* __restrict__ bofs,
    const int* __restrict__ totals, int* __restrict__ deg, float* __restrict__ dinv,
    int* __restrict__ ofs, int* __restrict__ csr,
    unsigned short* __restrict__ hn, int N)
{
    __shared__ int h[256];
    __shared__ int scn[256];
    __shared__ float sdv[256];
    int tid = threadIdx.x, k = blockIdx.x;
    int e0 = bofs[k], e1 = e0 + totals[k];
    int node = k * 256 + tid;

    h[tid] = 0;
    __syncthreads();
    for (int i = e0 + tid; i < e1; i += 256)
        atomicAdd(&h[bucketed[i] & 255], 1);
    __syncthreads();

    int mydeg = h[tid];
    scn[tid] = mydeg;
    __syncthreads();
    for (int d2 = 1; d2 < 256; d2 <<= 1) {
        int t = (tid >= d2) ? scn[tid - d2] : 0;
        __syncthreads();
        scn[tid] += t;
        __syncthreads();
    }
    int myofs = scn[tid] - mydeg;

    float dv = rsqrtf((float)(mydeg + 1));
    sdv[tid] = dv;
    if (node < N) {
        deg[node]  = mydeg;
        dinv[node] = dv;
        ofs[node]  = e0 + myofs;
    }

    h[tid] = myofs;                 // reuse as write cursor
    __syncthreads();
    for (int i = e0 + tid; i < e1; i += 256) {
        int v = bucketed[i];
        int pos = atomicAdd(&h[v & 255], 1);
        csr[e0 + pos] = v >> 8;
    }

    // scale this bucket's hn rows by dinv (in-place, bf16)
    __syncthreads();
    int4* hp = (int4*)hn;
    for (int c = tid; c < 2048; c += 256) {       // 256 rows x 8 int4 chunks
        int r = c >> 3;
        int n2 = k * 256 + r;
        if (n2 < N) {
            float f = sdv[r];
            size_t idx = (size_t)n2 * 8 + (c & 7);
            int4 hv = hp[idx];
            unsigned r0 = (unsigned)f2bf(bflo(hv.x) * f) | ((unsigned)f2bf(bfhi(hv.x) * f) << 16);
            unsigned r1 = (unsigned)f2bf(bflo(hv.y) * f) | ((unsigned)f2bf(bfhi(hv.y) * f) << 16);
            unsigned r2 = (unsigned)f2bf(bflo(hv.z) * f) | ((unsigned)f2bf(bfhi(hv.z) * f) << 16);
            unsigned r3 = (unsigned)f2bf(bflo(hv.w) * f) | ((unsigned)f2bf(bfhi(hv.w) * f) << 16);
            hp[idx] = make_int4((int)r0, (int)r1, (int)r2, (int)r3);
        }
    }
}

// =============== GEMM2: hn = bf16((h1 @ W) * dinv[row]) ===============
__global__ __launch_bounds__(256) void gemm2(
    const float* __restrict__ X, const float* __restrict__ W,
    const float* __restrict__ dinv, unsigned short* __restrict__ hn, int N)
{
    __shared__ float sW[D * D];
    __shared__ float sX[32 * D];
    int tid = threadIdx.x;
    int rowBase = blockIdx.x * 32;

    for (int i = tid; i < 1024; i += 256)
        ((vfloat4*)sW)[i] = ((const vfloat4*)W)[i];
    for (int i = tid; i < 512; i += 256) {
        int r = rowBase + (i >> 4);
        vfloat4 v = (vfloat4)0.0f;
        if (r < N) v = ((const vfloat4*)X)[rowBase * 16 + i];
        ((vfloat4*)sX)[i] = v;
    }
    __syncthreads();

    int wave = tid >> 6, lane = tid & 63;
    float accv[8];
#pragma unroll
    for (int r = 0; r < 8; ++r) accv[r] = 0.0f;
    int xoff = (wave * 8) * D;
#pragma unroll 8
    for (int k = 0; k < D; ++k) {
        float wv = sW[k * D + lane];
#pragma unroll
        for (int r = 0; r < 8; ++r)
            accv[r] += sX[xoff + r * D + k] * wv;
    }
#pragma unroll
    for (int r = 0; r < 8; ++r) {
        int row = rowBase + wave * 8 + r;
        if (row < N) hn[(size_t)row * D + lane] = f2bf(accv[r] * dinv[row]);
    }
}

// =============== aggregate (bf16 int4 gather) + epilogue ===============
// one wave per node; 8 groups x 8 lanes; shfl with all lanes active (uniform trips)
__global__ __launch_bounds__(256) void aggregate_relu(
    const int* __restrict__ ofs, const int* __restrict__ deg,
    const int* __restrict__ csr, const unsigned short* __restrict__ hn,
    const float* __restrict__ dinv, const float* __restrict__ bias,
    float* __restrict__ out, int N)
{
    int wid  = (int)((blockIdx.x * 256 + threadIdx.x) >> 6);
    int lane = threadIdx.x & 63;
    if (wid >= N) return;
    int grp = lane >> 3, sub = lane & 7;

    const int4* hrow = (const int4*)hn;
    float a0 = 0.f, a1 = 0.f, a2 = 0.f, a3 = 0.f,
          a4 = 0.f, a5 = 0.f, a6 = 0.f, a7 = 0.f;

    if (grp == 0) {                            // self loop (pre-scaled)
        int4 h = hrow[(size_t)wid * 8 + sub];
        a0 += bflo(h.x); a1 += bfhi(h.x); a2 += bflo(h.y); a3 += bfhi(h.y);
        a4 += bflo(h.z); a5 += bfhi(h.z); a6 += bflo(h.w); a7 += bfhi(h.w);
    }

    int s0 = ofs[wid];
    int cnt = deg[wid];

    for (int t0 = 0; t0 < cnt; t0 += 64) {
        int p = t0 + lane;
        int idx = (p < cnt) ? csr[s0 + p] : 0;
        int m = cnt - t0; if (m > 64) m = 64;
        int jmax = (m + 7) >> 3;
        for (int j = 0; j < jmax; ++j) {
            int pos = j * 8 + grp;
            int sn = __shfl(idx, pos, 64);
            if (pos < m) {
                int4 h = hrow[(size_t)sn * 8 + sub];
                a0 += bflo(h.x); a1 += bfhi(h.x); a2 += bflo(h.y); a3 += bfhi(h.y);
                a4 += bflo(h.z); a5 += bfhi(h.z); a6 += bflo(h.w); a7 += bfhi(h.w);
            }
        }
    }

#pragma unroll
    for (int d2 = 8; d2 < 64; d2 <<= 1) {
        a0 += __shfl_xor(a0, d2, 64); a1 += __shfl_xor(a1, d2, 64);
        a2 += __shfl_xor(a2, d2, 64); a3 += __shfl_xor(a3, d2, 64);
        a4 += __shfl_xor(a4, d2, 64); a5 += __shfl_xor(a5, d2, 64);
        a6 += __shfl_xor(a6, d2, 64); a7 += __shfl_xor(a7, d2, 64);
    }

    if (grp == 0) {
        float dw = dinv[wid];
        float4 b0 = ((const float4*)bias)[sub * 2];
        float4 b1 = ((const float4*)bias)[sub * 2 + 1];
        float4 o0, o1;
        o0.x = fmaxf(a0 * dw + b0.x, 0.f);
        o0.y = fmaxf(a1 * dw + b0.y, 0.f);
        o0.z = fmaxf(a2 * dw + b0.z, 0.f);
        o0.w = fmaxf(a3 * dw + b0.w, 0.f);
        o1.x = fmaxf(a4 * dw + b1.x, 0.f);
        o1.y = fmaxf(a5 * dw + b1.y, 0.f);
        o1.z = fmaxf(a6 * dw + b1.z, 0.f);
        o1.w = fmaxf(a7 * dw + b1.w, 0.f);
        ((float4*)out)[(size_t)wid * 16 + sub * 2]     = o0;
        ((float4*)out)[(size_t)wid * 16 + sub * 2 + 1] = o1;
    }
}

// =============== launcher ===============

extern "C" void kernel_launch(void* const* d_in, const int* in_sizes, int n_in,
                              void* d_out, int out_size, void* d_ws, size_t ws_size,
                              hipStream_t stream) {
    const float* x   = (const float*)d_in[0];
    const int*   ei  = (const int*)d_in[1];   // [2, E] int32
    const float* W1  = (const float*)d_in[2];
    const float* b1  = (const float*)d_in[3];
    const float* W2  = (const float*)d_in[4];
    const float* b2  = (const float*)d_in[5];

    int N = in_sizes[0] / D;
    int E = in_sizes[1] / 2;
    const int* src = ei;
    const int* dst = ei + E;
    int NBK = (N + 255) >> 8;                 // 391 buckets for N=100000

    // workspace layout (bytes, ~30 MB total; ws >= 46 MB verified round 5)
    char* ws = (char*)d_ws;
    int*            blockCounts = (int*)(ws + 0x00000000);  // NB_HIST*NBK (400 KB)
    int*            partial     = (int*)(ws + 0x00080000);  // NBK*NB_HIST (400 KB)
    int*            totals      = (int*)(ws + 0x00100000);  // NBK
    int*            bofs        = (int*)(ws + 0x00110000);  // NBK
    int*            deg         = (int*)(ws + 0x00120000);  // N
    float*          dinv        = (float*)(ws + 0x00190000);// N
    int*            ofs         = (int*)(ws + 0x00200000);  // N
    int*            bucketed    = (int*)(ws + 0x00280000);  // E (6.4 MB)
    int*            csr         = (int*)(ws + 0x00A00000);  // E (6.4 MB)
    unsigned short* hn          = (unsigned short*)(ws + 0x01100000); // N*D bf16 (12.8 MB)
    float*          outF        = (float*)d_out;

    int nb_G = (N + 31) / 32;
    int nb_A = (N + 3) / 4;

    // pass A: bucket histograms + GEMM1 (fused)
    passA_gemm<<<NB_HIST + nb_G, 256, 0, stream>>>(dst, blockCounts, E, NBK, x, W1, hn, N);
    // C1 + C2: cursor scans
    scan_cols<<<(NBK + 3) / 4, 256, 0, stream>>>(blockCounts, partial, totals, NBK);
    scan_buckets<<<1, 64, 0, stream>>>(totals, bofs, NBK);
    // pass B: bucket-grouped edge scatter
    passB<<<NB_HIST, 256, 0, stream>>>(src, dst, bofs, partial, bucketed, E, NBK);
    // level 2: CSR + deg/dinv/ofs + hn scale
    build_csr_scale<<<NBK, 256, 0, stream>>>(bucketed, bofs, totals, deg, dinv, ofs, csr, hn, N);

    // layer 1 aggregate -> h1 (fp32, in d_out)
    aggregate_relu<<<nb_A, 256, 0, stream>>>(ofs, deg, csr, hn, dinv, b1, outF, N);
    // layer 2 GEMM: hn = bf16((h1 @ W2) * dinv)
    gemm2<<<nb_G, 256, 0, stream>>>(outF, W2, dinv, hn, N);
    // layer 2 aggregate -> final out (in place over h1)
    aggregate_relu<<<nb_A, 256, 0, stream>>>(ofs, deg, csr, hn, dinv, b2, outF, N);
}

// Round 10
// 242.794 us; speedup vs baseline: 1.3756x; 1.1322x over previous
//
#include <hip/hip_runtime.h>
#include <hip/hip_bf16.h>

#define D 64
#define NB_HIST 256          // partition blocks (fixed ranges, pass A == pass B)
#define MAXBK 512            // supports N <= 131072 (buckets of 256 nodes)

typedef float vfloat4 __attribute__((ext_vector_type(4)));

__device__ __forceinline__ unsigned short f2bf(float f) {
    union { float f; unsigned u; } v; v.f = f;
    unsigned r = (v.u + 0x7FFF + ((v.u >> 16) & 1)) >> 16;   // RNE
    return (unsigned short)r;
}
__device__ __forceinline__ float bflo(unsigned u) {
    union { unsigned u; float f; } v; v.u = u << 16; return v.f;
}
__device__ __forceinline__ float bfhi(unsigned u) {
    union { unsigned u; float f; } v; v.u = u & 0xFFFF0000u; return v.f;
}

// =============== pass A: fused {per-block LDS bucket histogram} + GEMM1 ===============
__global__ __launch_bounds__(256) void passA_gemm(
    const int* __restrict__ dst, int* __restrict__ blockCounts, int E, int per, int NBK,
    const float* __restrict__ X, const float* __restrict__ W,
    unsigned short* __restrict__ hn, int N)
{
    int tid = threadIdx.x;

    if ((int)blockIdx.x < NB_HIST) {
        __shared__ int hist[MAXBK];
        for (int i = tid; i < NBK; i += 256) hist[i] = 0;
        __syncthreads();
        int lo = blockIdx.x * per, hi = min(E, lo + per);   // per % 4 == 0, lo 16B-aligned
        for (int i = lo + tid * 4; i < hi; i += 1024) {
            if (i + 3 < hi) {
                int4 d4 = *(const int4*)(dst + i);
                atomicAdd(&hist[d4.x >> 8], 1);
                atomicAdd(&hist[d4.y >> 8], 1);
                atomicAdd(&hist[d4.z >> 8], 1);
                atomicAdd(&hist[d4.w >> 8], 1);
            } else {
                for (int k = i; k < hi; ++k) atomicAdd(&hist[dst[k] >> 8], 1);
            }
        }
        __syncthreads();
        for (int i = tid; i < NBK; i += 256)
            blockCounts[(size_t)blockIdx.x * NBK + i] = hist[i];
        return;
    }

    __shared__ float sW[D * D];
    __shared__ float sX[32 * D];
    int rowBase = ((int)blockIdx.x - NB_HIST) * 32;

    for (int i = tid; i < 1024; i += 256)
        ((vfloat4*)sW)[i] = ((const vfloat4*)W)[i];
    for (int i = tid; i < 512; i += 256) {
        int r = rowBase + (i >> 4);
        vfloat4 v = (vfloat4)0.0f;
        if (r < N) v = __builtin_nontemporal_load(((const vfloat4*)X) + rowBase * 16 + i);
        ((vfloat4*)sX)[i] = v;
    }
    __syncthreads();

    int wave = tid >> 6, lane = tid & 63;
    float accv[8];
#pragma unroll
    for (int r = 0; r < 8; ++r) accv[r] = 0.0f;
    int xoff = (wave * 8) * D;
#pragma unroll 8
    for (int k = 0; k < D; ++k) {
        float wv = sW[k * D + lane];
#pragma unroll
        for (int r = 0; r < 8; ++r)
            accv[r] += sX[xoff + r * D + k] * wv;
    }
#pragma unroll
    for (int r = 0; r < 8; ++r) {
        int row = rowBase + wave * 8 + r;
        if (row < N) hn[(size_t)row * D + lane] = f2bf(accv[r]);
    }
}

// =============== C1: per-bucket exclusive scan over the 256 blocks ===============
__global__ __launch_bounds__(256) void scan_cols(
    const int* __restrict__ blockCounts, int* __restrict__ partial,
    int* __restrict__ totals, int NBK)
{
    int wave = threadIdx.x >> 6, lane = threadIdx.x & 63;
    int k = blockIdx.x * 4 + wave;
    if (k >= NBK) return;
    int carry = 0;
    for (int base = 0; base < NB_HIST; base += 64) {
        int b = base + lane;
        int v = blockCounts[(size_t)b * NBK + k];
        int inc = v;
        for (int d = 1; d < 64; d <<= 1) {
            int t = __shfl_up(inc, d, 64);
            if (lane >= d) inc += t;
        }
        partial[(size_t)k * NB_HIST + b] = inc - v + carry;
        carry += __shfl(inc, 63, 64);
    }
    if (lane == 0) totals[k] = carry;
}

// =============== C2: exclusive scan of bucket totals (single wave) ===============
__global__ void scan_buckets(const int* __restrict__ totals, int* __restrict__ bofs, int NBK) {
    int lane = threadIdx.x;
    int carry = 0;
    for (int base = 0; base < NBK; base += 64) {
        int i = base + lane;
        int v = (i < NBK) ? totals[i] : 0;
        int inc = v;
        for (int d = 1; d < 64; d <<= 1) {
            int t = __shfl_up(inc, d, 64);
            if (lane >= d) inc += t;
        }
        if (i < NBK) bofs[i] = inc - v + carry;
        carry += __shfl(inc, 63, 64);
    }
}

// =============== pass B: scatter edges into bucket-grouped order (LDS cursors) ===============
__global__ __launch_bounds__(256) void passB(
    const int* __restrict__ src, const int* __restrict__ dst,
    const int* __restrict__ bofs, const int* __restrict__ partial,
    int* __restrict__ bucketed, int E, int per, int NBK)
{
    __shared__ int cur[MAXBK];
    int tid = threadIdx.x, b = blockIdx.x;
    for (int i = tid; i < NBK; i += 256)
        cur[i] = bofs[i] + partial[(size_t)i * NB_HIST + b];
    __syncthreads();
    int lo = b * per, hi = min(E, lo + per);
    for (int i = lo + tid * 4; i < hi; i += 1024) {
        if (i + 3 < hi) {
            int4 d4 = *(const int4*)(dst + i);
            int4 s4 = *(const int4*)(src + i);
            int p0 = atomicAdd(&cur[d4.x >> 8], 1);
            int p1 = atomicAdd(&cur[d4.y >> 8], 1);
            int p2 = atomicAdd(&cur[d4.z >> 8], 1);
            int p3 = atomicAdd(&cur[d4.w >> 8], 1);
            bucketed[p0] = (s4.x << 8) | (d4.x & 255);
            bucketed[p1] = (s4.y << 8) | (d4.y & 255);
            bucketed[p2] = (s4.z << 8) | (d4.z & 255);
            bucketed[p3] = (s4.w << 8) | (d4.w & 255);
        } else {
            for (int k = i; k < hi; ++k) {
                int d = dst[k], s = src[k];
                int pos = atomicAdd(&cur[d >> 8], 1);
                bucketed[pos] = (s << 8) | (d & 255);
            }
        }
    }
}

// =============== level 2: per-bucket CSR build + deg/dinv/ofs + hn scale ===============
__global__ __launch_bounds__(256) void build_csr_scale(
    const int* __restrict__ bucketed, const int* __restrict__ bofs,
    const int* __restrict__ totals, int* __restrict__ deg, float* __restrict__ dinv,
    int* __restrict__ ofs, int* __restrict__ csr,
    unsigned short* __restrict__ hn, int N)
{
    __shared__ int h[256];
    __shared__ int scn[256];
    __shared__ float sdv[256];
    int tid = threadIdx.x, k = blockIdx.x;
    int e0 = bofs[k], e1 = e0 + totals[k];
    int node = k * 256 + tid;

    h[tid] = 0;
    __syncthreads();
    for (int i = e0 + tid; i < e1; i += 256)
        atomicAdd(&h[bucketed[i] & 255], 1);
    __syncthreads();

    int mydeg = h[tid];
    scn[tid] = mydeg;
    __syncthreads();
    for (int d2 = 1; d2 < 256; d2 <<= 1) {
        int t = (tid >= d2) ? scn[tid - d2] : 0;
        __syncthreads();
        scn[tid] += t;
        __syncthreads();
    }
    int myofs = scn[tid] - mydeg;

    float dv = rsqrtf((float)(mydeg + 1));
    sdv[tid] = dv;
    if (node < N) {
        deg[node]  = mydeg;
        dinv[node] = dv;
        ofs[node]  = e0 + myofs;
    }

    h[tid] = myofs;                 // reuse as write cursor
    __syncthreads();
    for (int i = e0 + tid; i < e1; i += 256) {
        int v = bucketed[i];
        int pos = atomicAdd(&h[v & 255], 1);
        csr[e0 + pos] = v >> 8;
    }

    __syncthreads();
    int4* hp = (int4*)hn;
    for (int c = tid; c < 2048; c += 256) {       // 256 rows x 8 int4 chunks
        int r = c >> 3;
        int n2 = k * 256 + r;
        if (n2 < N) {
            float f = sdv[r];
            size_t idx = (size_t)n2 * 8 + (c & 7);
            int4 hv = hp[idx];
            unsigned r0 = (unsigned)f2bf(bflo(hv.x) * f) | ((unsigned)f2bf(bfhi(hv.x) * f) << 16);
            unsigned r1 = (unsigned)f2bf(bflo(hv.y) * f) | ((unsigned)f2bf(bfhi(hv.y) * f) << 16);
            unsigned r2 = (unsigned)f2bf(bflo(hv.z) * f) | ((unsigned)f2bf(bfhi(hv.z) * f) << 16);
            unsigned r3 = (unsigned)f2bf(bflo(hv.w) * f) | ((unsigned)f2bf(bfhi(hv.w) * f) << 16);
            hp[idx] = make_int4((int)r0, (int)r1, (int)r2, (int)r3);
        }
    }
}

// =============== GEMM2: hn = bf16((h1 @ W) * dinv[row]) ===============
__global__ __launch_bounds__(256) void gemm2(
    const float* __restrict__ X, const float* __restrict__ W,
    const float* __restrict__ dinv, unsigned short* __restrict__ hn, int N)
{
    __shared__ float sW[D * D];
    __shared__ float sX[32 * D];
    int tid = threadIdx.x;
    int rowBase = blockIdx.x * 32;

    for (int i = tid; i < 1024; i += 256)
        ((vfloat4*)sW)[i] = ((const vfloat4*)W)[i];
    for (int i = tid; i < 512; i += 256) {
        int r = rowBase + (i >> 4);
        vfloat4 v = (vfloat4)0.0f;
        if (r < N) v = ((const vfloat4*)X)[rowBase * 16 + i];
        ((vfloat4*)sX)[i] = v;
    }
    __syncthreads();

    int wave = tid >> 6, lane = tid & 63;
    float accv[8];
#pragma unroll
    for (int r = 0; r < 8; ++r) accv[r] = 0.0f;
    int xoff = (wave * 8) * D;
#pragma unroll 8
    for (int k = 0; k < D; ++k) {
        float wv = sW[k * D + lane];
#pragma unroll
        for (int r = 0; r < 8; ++r)
            accv[r] += sX[xoff + r * D + k] * wv;
    }
#pragma unroll
    for (int r = 0; r < 8; ++r) {
        int row = rowBase + wave * 8 + r;
        if (row < N) hn[(size_t)row * D + lane] = f2bf(accv[r] * dinv[row]);
    }
}

// =============== aggregate: one 8-lane group per node, 8 nodes per wave ===============
// lane sub owns cols sub*8..sub*8+7 (one int4 of the bf16 row); group's accs are
// final for its node -> NO cross-group reduction, NO shfl (index via 8-lane
// broadcast load). hn pre-scaled by dinv[src]; out = relu(acc*dinv[node] + b).
__global__ __launch_bounds__(256) void aggregate_relu(
    const int* __restrict__ ofs, const int* __restrict__ deg,
    const int* __restrict__ csr, const unsigned short* __restrict__ hn,
    const float* __restrict__ dinv, const float* __restrict__ bias,
    float* __restrict__ out, int N)
{
    int t    = blockIdx.x * 256 + threadIdx.x;
    int lane = threadIdx.x & 63;
    int grp  = lane >> 3, sub = lane & 7;
    int node = (t >> 6) * 8 + grp;
    bool live = (node < N);

    const int4* hrow = (const int4*)hn;
    float2 a0 = {0.f, 0.f}, a1 = {0.f, 0.f}, a2 = {0.f, 0.f}, a3 = {0.f, 0.f};

    int s0 = 0, cnt = 0;
    if (live) {
        s0  = ofs[node];
        cnt = deg[node];
        int4 h = hrow[(size_t)node * 8 + sub];       // self loop (pre-scaled)
        a0.x += bflo(h.x); a0.y += bfhi(h.x);
        a1.x += bflo(h.y); a1.y += bfhi(h.y);
        a2.x += bflo(h.z); a2.y += bfhi(h.z);
        a3.x += bflo(h.w); a3.y += bfhi(h.w);
    }

    const int* cp = csr + s0;
    int j = 0;
    for (; j + 1 < cnt; j += 2) {                    // 2 gathers in flight per group
        int sA = cp[j], sB = cp[j + 1];              // broadcast within group
        int4 hA = hrow[(size_t)sA * 8 + sub];
        int4 hB = hrow[(size_t)sB * 8 + sub];
        a0.x += bflo(hA.x); a0.y += bfhi(hA.x);
        a1.x += bflo(hA.y); a1.y += bfhi(hA.y);
        a2.x += bflo(hA.z); a2.y += bfhi(hA.z);
        a3.x += bflo(hA.w); a3.y += bfhi(hA.w);
        a0.x += bflo(hB.x); a0.y += bfhi(hB.x);
        a1.x += bflo(hB.y); a1.y += bfhi(hB.y);
        a2.x += bflo(hB.z); a2.y += bfhi(hB.z);
        a3.x += bflo(hB.w); a3.y += bfhi(hB.w);
    }
    if (j < cnt) {
        int sA = cp[j];
        int4 hA = hrow[(size_t)sA * 8 + sub];
        a0.x += bflo(hA.x); a0.y += bfhi(hA.x);
        a1.x += bflo(hA.y); a1.y += bfhi(hA.y);
        a2.x += bflo(hA.z); a2.y += bfhi(hA.z);
        a3.x += bflo(hA.w); a3.y += bfhi(hA.w);
    }

    if (live) {
        float dw = dinv[node];
        float4 b0 = ((const float4*)bias)[sub * 2];
        float4 b1 = ((const float4*)bias)[sub * 2 + 1];
        float4 o0, o1;
        o0.x = fmaxf(a0.x * dw + b0.x, 0.f);
        o0.y = fmaxf(a0.y * dw + b0.y, 0.f);
        o0.z = fmaxf(a1.x * dw + b0.z, 0.f);
        o0.w = fmaxf(a1.y * dw + b0.w, 0.f);
        o1.x = fmaxf(a2.x * dw + b1.x, 0.f);
        o1.y = fmaxf(a2.y * dw + b1.y, 0.f);
        o1.z = fmaxf(a3.x * dw + b1.z, 0.f);
        o1.w = fmaxf(a3.y * dw + b1.w, 0.f);
        ((float4*)out)[(size_t)node * 16 + sub * 2]     = o0;
        ((float4*)out)[(size_t)node * 16 + sub * 2 + 1] = o1;
    }
}

// =============== launcher ===============

extern "C" void kernel_launch(void* const* d_in, const int* in_sizes, int n_in,
                              void* d_out, int out_size, void* d_ws, size_t ws_size,
                              hipStream_t stream) {
    const float* x   = (const float*)d_in[0];
    const int*   ei  = (const int*)d_in[1];   // [2, E] int32
    const float* b1  = (const float*)d_in[3];
    const float* W1  = (const float*)d_in[2];
    const float* W2  = (const float*)d_in[4];
    const float* b2  = (const float*)d_in[5];

    int N = in_sizes[0] / D;
    int E = in_sizes[1] / 2;
    const int* src = ei;
    const int* dst = ei + E;
    int NBK = (N + 255) >> 8;                 // 391 buckets for N=100000
    int per = (((E + NB_HIST - 1) / NB_HIST) + 3) & ~3;   // edges per partition block (x4 aligned)

    // workspace layout (bytes, ~30 MB)
    char* ws = (char*)d_ws;
    int*            blockCounts = (int*)(ws + 0x00000000);  // NB_HIST*NBK
    int*            partial     = (int*)(ws + 0x00080000);  // NBK*NB_HIST
    int*            totals      = (int*)(ws + 0x00100000);  // NBK
    int*            bofs        = (int*)(ws + 0x00110000);  // NBK
    int*            deg         = (int*)(ws + 0x00120000);  // N
    float*          dinv        = (float*)(ws + 0x00190000);// N
    int*            ofs         = (int*)(ws + 0x00200000);  // N
    int*            bucketed    = (int*)(ws + 0x00280000);  // E
    int*            csr         = (int*)(ws + 0x00A00000);  // E
    unsigned short* hn          = (unsigned short*)(ws + 0x01100000); // N*D bf16
    float*          outF        = (float*)d_out;

    int nb_G = (N + 31) / 32;
    int nb_A = (N + 31) / 32;                 // agg: 8 nodes/wave, 32/block

    passA_gemm<<<NB_HIST + nb_G, 256, 0, stream>>>(dst, blockCounts, E, per, NBK, x, W1, hn, N);
    scan_cols<<<(NBK + 3) / 4, 256, 0, stream>>>(blockCounts, partial, totals, NBK);
    scan_buckets<<<1, 64, 0, stream>>>(totals, bofs, NBK);
    passB<<<NB_HIST, 256, 0, stream>>>(src, dst, bofs, partial, bucketed, E, per, NBK);
    build_csr_scale<<<NBK, 256, 0, stream>>>(bucketed, bofs, totals, deg, dinv, ofs, csr, hn, N);

    aggregate_relu<<<nb_A, 256, 0, stream>>>(ofs, deg, csr, hn, dinv, b1, outF, N);
    gemm2<<<nb_G, 256, 0, stream>>>(outF, W2, dinv, hn, N);
    aggregate_relu<<<nb_A, 256, 0, stream>>>(ofs, deg, csr, hn, dinv, b2, outF, N);
}